// Round 1
// baseline (98.848 us; speedup 1.0000x reference)
//
#include <hip/hip_runtime.h>

// 4-qubit, 2-layer RY/CNOT circuit + Z-expectations + 4->2 linear head.
// One thread per batch element; the 16-amplitude state lives in registers.
//
// State index convention (matches jnp (B,2,2,2,2), qubit q on axis 1+q):
//   s = (b0<<3) | (b1<<2) | (b2<<1) | b3   -> qubit q uses bit (8>>q).

template<int BIT>
__device__ __forceinline__ void apply_ry(float (&a)[16], float c, float s) {
#pragma unroll
    for (int i = 0; i < 16; ++i) {
        if ((i & BIT) == 0) {
            float a0 = a[i];
            float a1 = a[i | BIT];
            a[i]       = __builtin_fmaf(c, a0, -(s * a1));  // c*a0 - s*a1
            a[i | BIT] = __builtin_fmaf(s, a0,  (c * a1));  // s*a0 + c*a1
        }
    }
}

template<int CBIT, int TBIT>
__device__ __forceinline__ void apply_cnot(float (&a)[16]) {
#pragma unroll
    for (int i = 0; i < 16; ++i) {
        if ((i & CBIT) != 0 && (i & TBIT) == 0) {
            float t = a[i];
            a[i] = a[i | TBIT];
            a[i | TBIT] = t;
        }
    }
}

__global__ __launch_bounds__(256) void qsim_kernel(
    const float4* __restrict__ x4,    // (B,4) viewed as float4 per row
    const float*  __restrict__ wts,   // (2,4) circuit weights
    const float*  __restrict__ W,     // (2,4) linear weights, row-major
    const float*  __restrict__ bias,  // (2,)
    float2*       __restrict__ out,   // (B,2) viewed as float2 per row
    int B)
{
    int i = blockIdx.x * blockDim.x + threadIdx.x;
    if (i >= B) return;

    float4 xa = x4[i];

    // sincos of half-angles for the per-sample initial RYs
    float c0, s0, c1, s1, c2, s2, c3, s3;
    __sincosf(0.5f * xa.x, &s0, &c0);
    __sincosf(0.5f * xa.y, &s1, &c1);
    __sincosf(0.5f * xa.z, &s2, &c2);
    __sincosf(0.5f * xa.w, &s3, &c3);

    // sincos of half-angles for the (uniform) weight RYs
    float cw[8], sw[8];
#pragma unroll
    for (int k = 0; k < 8; ++k) {
        __sincosf(0.5f * wts[k], &sw[k], &cw[k]);
    }

    // Initial state after 4 RYs on |0000>: rank-1 tensor product.
    float a[16];
    {
        float p00 = c0 * c1, p01 = c0 * s1, p10 = s0 * c1, p11 = s0 * s1; // (q0,q1)
        float q00 = c2 * c3, q01 = c2 * s3, q10 = s2 * c3, q11 = s2 * s3; // (q2,q3)
        a[ 0] = p00 * q00; a[ 1] = p00 * q01; a[ 2] = p00 * q10; a[ 3] = p00 * q11;
        a[ 4] = p01 * q00; a[ 5] = p01 * q01; a[ 6] = p01 * q10; a[ 7] = p01 * q11;
        a[ 8] = p10 * q00; a[ 9] = p10 * q01; a[10] = p10 * q10; a[11] = p10 * q11;
        a[12] = p11 * q00; a[13] = p11 * q01; a[14] = p11 * q10; a[15] = p11 * q11;
    }

    // 2 layers: CNOT ring (0->1,1->2,2->3,3->0) then RY(weights[l][q]) on each q.
#pragma unroll
    for (int l = 0; l < 2; ++l) {
        apply_cnot<8, 4>(a);   // CNOT(0,1)
        apply_cnot<4, 2>(a);   // CNOT(1,2)
        apply_cnot<2, 1>(a);   // CNOT(2,3)
        apply_cnot<1, 8>(a);   // CNOT(3,0)
        apply_ry<8>(a, cw[l * 4 + 0], sw[l * 4 + 0]);  // qubit 0
        apply_ry<4>(a, cw[l * 4 + 1], sw[l * 4 + 1]);  // qubit 1
        apply_ry<2>(a, cw[l * 4 + 2], sw[l * 4 + 2]);  // qubit 2
        apply_ry<1>(a, cw[l * 4 + 3], sw[l * 4 + 3]);  // qubit 3
    }

    // <Z_q> = sum_s (+/-) a[s]^2, sign from bit (8>>q) of s.
    float z0 = 0.f, z1 = 0.f, z2 = 0.f, z3 = 0.f;
#pragma unroll
    for (int s = 0; s < 16; ++s) {
        float p = a[s] * a[s];
        z0 += (s & 8) ? -p : p;
        z1 += (s & 4) ? -p : p;
        z2 += (s & 2) ? -p : p;
        z3 += (s & 1) ? -p : p;
    }

    // Linear head: out[j] = z . W[j,:] + bias[j]
    float o0 = bias[0];
    o0 = __builtin_fmaf(z0, W[0], o0);
    o0 = __builtin_fmaf(z1, W[1], o0);
    o0 = __builtin_fmaf(z2, W[2], o0);
    o0 = __builtin_fmaf(z3, W[3], o0);
    float o1 = bias[1];
    o1 = __builtin_fmaf(z0, W[4], o1);
    o1 = __builtin_fmaf(z1, W[5], o1);
    o1 = __builtin_fmaf(z2, W[6], o1);
    o1 = __builtin_fmaf(z3, W[7], o1);

    out[i] = make_float2(o0, o1);
}

extern "C" void kernel_launch(void* const* d_in, const int* in_sizes, int n_in,
                              void* d_out, int out_size, void* d_ws, size_t ws_size,
                              hipStream_t stream) {
    const float* x    = (const float*)d_in[0];  // (B,4)
    const float* wts  = (const float*)d_in[1];  // (2,4)
    const float* W    = (const float*)d_in[2];  // (2,4)
    const float* bias = (const float*)d_in[3];  // (2,)
    float* out = (float*)d_out;                 // (B,2)

    int B = in_sizes[0] / 4;
    int block = 256;
    int grid = (B + block - 1) / block;
    qsim_kernel<<<grid, block, 0, stream>>>(
        (const float4*)x, wts, W, bias, (float2*)out, B);
}

// Round 3
// 96.224 us; speedup vs baseline: 1.0273x; 1.0273x over previous
//
#include <hip/hip_runtime.h>

// 4-qubit, 2-layer RY/CNOT circuit + Z-expectations + 4->2 linear head.
// One thread per batch element; 16-amplitude state in registers.
//
// Index convention: s bit (8>>q) is qubit q (axis 1+q of the (B,2,2,2,2) ref).
//
// Layer-2 RYs are fused into the readout via
//   <Z_q>(R phi) = cos(th_q) * sum_pairs(phi0^2 - phi1^2)
//                - 2 sin(th_q) * sum_pairs(phi0*phi1)
// (rotations on other qubits cancel: R_r^T Z_q R_r = Z_q for r != q), and the
// linear head W, bias are folded into the per-qubit coefficients.
//
// Nontemporal builtins need clang-native vectors, not HIP_vector_type.
typedef float vfloat4 __attribute__((ext_vector_type(4)));
typedef float vfloat2 __attribute__((ext_vector_type(2)));

template<int BIT>
__device__ __forceinline__ void apply_ry(float (&a)[16], float c, float s) {
#pragma unroll
    for (int i = 0; i < 16; ++i) {
        if ((i & BIT) == 0) {
            float a0 = a[i];
            float a1 = a[i | BIT];
            a[i]       = __builtin_fmaf(c, a0, -(s * a1));  // c*a0 - s*a1
            a[i | BIT] = __builtin_fmaf(s, a0,  (c * a1));  // s*a0 + c*a1
        }
    }
}

template<int CBIT, int TBIT>
__device__ __forceinline__ void apply_cnot(float (&a)[16]) {
#pragma unroll
    for (int i = 0; i < 16; ++i) {
        if ((i & CBIT) != 0 && (i & TBIT) == 0) {
            float t = a[i];
            a[i] = a[i | TBIT];
            a[i | TBIT] = t;
        }
    }
}

__global__ __launch_bounds__(256) void qsim_kernel(
    const vfloat4* __restrict__ x4,   // (B,4) as float4 rows
    const float*  __restrict__ wts,   // (2,4) circuit weights
    const float*  __restrict__ W,     // (2,4) linear weights
    const float*  __restrict__ bias,  // (2,)
    vfloat2*      __restrict__ out,   // (B,2) as float2 rows
    int B)
{
    int i = blockIdx.x * blockDim.x + threadIdx.x;
    if (i >= B) return;

    // ---- uniform (batch-independent) precompute; scalar loads, cheap ----
    float cw[4], sw[4];                 // layer-1 half-angle trig
#pragma unroll
    for (int q = 0; q < 4; ++q) {
        __sincosf(0.5f * wts[q], &sw[q], &cw[q]);
    }
    float wc0[4], wc1[4], wsn0[4], wsn1[4];  // layer-2 fused coefficients
#pragma unroll
    for (int q = 0; q < 4; ++q) {
        float S, C;
        __sincosf(wts[4 + q], &S, &C);       // FULL angle for the fused form
        wc0[q]  = W[q]     * C;
        wc1[q]  = W[4 + q] * C;
        wsn0[q] = -2.0f * W[q]     * S;
        wsn1[q] = -2.0f * W[4 + q] * S;
    }
    float b0 = bias[0], b1 = bias[1];

    // ---- per-sample initial RYs on |0000>: rank-1 product state ----
    vfloat4 xa = __builtin_nontemporal_load(&x4[i]);
    float c0, s0, c1, s1, c2, s2, c3, s3;
    __sincosf(0.5f * xa.x, &s0, &c0);
    __sincosf(0.5f * xa.y, &s1, &c1);
    __sincosf(0.5f * xa.z, &s2, &c2);
    __sincosf(0.5f * xa.w, &s3, &c3);

    float a[16];
    {
        float p00 = c0 * c1, p01 = c0 * s1, p10 = s0 * c1, p11 = s0 * s1;
        float q00 = c2 * c3, q01 = c2 * s3, q10 = s2 * c3, q11 = s2 * s3;
        a[ 0] = p00 * q00; a[ 1] = p00 * q01; a[ 2] = p00 * q10; a[ 3] = p00 * q11;
        a[ 4] = p01 * q00; a[ 5] = p01 * q01; a[ 6] = p01 * q10; a[ 7] = p01 * q11;
        a[ 8] = p10 * q00; a[ 9] = p10 * q01; a[10] = p10 * q10; a[11] = p10 * q11;
        a[12] = p11 * q00; a[13] = p11 * q01; a[14] = p11 * q10; a[15] = p11 * q11;
    }

    // ---- layer 1: CNOT ring (free register renames) + 4 RYs ----
    apply_cnot<8, 4>(a);
    apply_cnot<4, 2>(a);
    apply_cnot<2, 1>(a);
    apply_cnot<1, 8>(a);
    apply_ry<8>(a, cw[0], sw[0]);
    apply_ry<4>(a, cw[1], sw[1]);
    apply_ry<2>(a, cw[2], sw[2]);
    apply_ry<1>(a, cw[3], sw[3]);

    // ---- layer 2 CNOTs (free); RYs fused into readout below ----
    apply_cnot<8, 4>(a);
    apply_cnot<4, 2>(a);
    apply_cnot<2, 1>(a);
    apply_cnot<1, 8>(a);

    // ---- squared amplitudes + signed-sum (Walsh) tree for dz_q ----
    float p[16];
#pragma unroll
    for (int s = 0; s < 16; ++s) p[s] = a[s] * a[s];

    float A[8], D[8];
#pragma unroll
    for (int t = 0; t < 8; ++t) { A[t] = p[t] + p[t + 8]; D[t] = p[t] - p[t + 8]; }
    float dz0 = ((D[0] + D[1]) + (D[2] + D[3])) + ((D[4] + D[5]) + (D[6] + D[7]));

    float A2[4], D2[4];
#pragma unroll
    for (int t = 0; t < 4; ++t) { A2[t] = A[t] + A[t + 4]; D2[t] = A[t] - A[t + 4]; }
    float dz1 = (D2[0] + D2[1]) + (D2[2] + D2[3]);
    float dz2 = (A2[0] - A2[2]) + (A2[1] - A2[3]);
    float dz3 = (A2[0] + A2[2]) - (A2[1] + A2[3]);

    // ---- cross terms xz_q = sum over (i, i|bit) pairs of a_i * a_j ----
    float xz0 = a[0] * a[8];
#pragma unroll
    for (int t = 1; t < 8; ++t) xz0 = __builtin_fmaf(a[t], a[t + 8], xz0);

    float xz1 = a[0] * a[4];
    xz1 = __builtin_fmaf(a[1], a[5], xz1);
    xz1 = __builtin_fmaf(a[2], a[6], xz1);
    xz1 = __builtin_fmaf(a[3], a[7], xz1);
    xz1 = __builtin_fmaf(a[8], a[12], xz1);
    xz1 = __builtin_fmaf(a[9], a[13], xz1);
    xz1 = __builtin_fmaf(a[10], a[14], xz1);
    xz1 = __builtin_fmaf(a[11], a[15], xz1);

    float xz2 = a[0] * a[2];
    xz2 = __builtin_fmaf(a[1],  a[3],  xz2);
    xz2 = __builtin_fmaf(a[4],  a[6],  xz2);
    xz2 = __builtin_fmaf(a[5],  a[7],  xz2);
    xz2 = __builtin_fmaf(a[8],  a[10], xz2);
    xz2 = __builtin_fmaf(a[9],  a[11], xz2);
    xz2 = __builtin_fmaf(a[12], a[14], xz2);
    xz2 = __builtin_fmaf(a[13], a[15], xz2);

    float xz3 = a[0] * a[1];
    xz3 = __builtin_fmaf(a[2],  a[3],  xz3);
    xz3 = __builtin_fmaf(a[4],  a[5],  xz3);
    xz3 = __builtin_fmaf(a[6],  a[7],  xz3);
    xz3 = __builtin_fmaf(a[8],  a[9],  xz3);
    xz3 = __builtin_fmaf(a[10], a[11], xz3);
    xz3 = __builtin_fmaf(a[12], a[13], xz3);
    xz3 = __builtin_fmaf(a[14], a[15], xz3);

    // ---- fused head: out_j = b_j + sum_q W[j,q]*C_q*dz_q - 2*W[j,q]*S_q*xz_q
    float o0 = b0;
    o0 = __builtin_fmaf(wc0[0], dz0, o0);
    o0 = __builtin_fmaf(wc0[1], dz1, o0);
    o0 = __builtin_fmaf(wc0[2], dz2, o0);
    o0 = __builtin_fmaf(wc0[3], dz3, o0);
    o0 = __builtin_fmaf(wsn0[0], xz0, o0);
    o0 = __builtin_fmaf(wsn0[1], xz1, o0);
    o0 = __builtin_fmaf(wsn0[2], xz2, o0);
    o0 = __builtin_fmaf(wsn0[3], xz3, o0);

    float o1 = b1;
    o1 = __builtin_fmaf(wc1[0], dz0, o1);
    o1 = __builtin_fmaf(wc1[1], dz1, o1);
    o1 = __builtin_fmaf(wc1[2], dz2, o1);
    o1 = __builtin_fmaf(wc1[3], dz3, o1);
    o1 = __builtin_fmaf(wsn1[0], xz0, o1);
    o1 = __builtin_fmaf(wsn1[1], xz1, o1);
    o1 = __builtin_fmaf(wsn1[2], xz2, o1);
    o1 = __builtin_fmaf(wsn1[3], xz3, o1);

    vfloat2 o; o.x = o0; o.y = o1;
    __builtin_nontemporal_store(o, &out[i]);
}

extern "C" void kernel_launch(void* const* d_in, const int* in_sizes, int n_in,
                              void* d_out, int out_size, void* d_ws, size_t ws_size,
                              hipStream_t stream) {
    const float* x    = (const float*)d_in[0];  // (B,4)
    const float* wts  = (const float*)d_in[1];  // (2,4)
    const float* W    = (const float*)d_in[2];  // (2,4)
    const float* bias = (const float*)d_in[3];  // (2,)
    float* out = (float*)d_out;                 // (B,2)

    int B = in_sizes[0] / 4;
    int block = 256;
    int grid = (B + block - 1) / block;
    qsim_kernel<<<grid, block, 0, stream>>>(
        (const vfloat4*)x, wts, W, bias, (vfloat2*)out, B);
}

// Round 4
// 93.760 us; speedup vs baseline: 1.0543x; 1.0263x over previous
//
#include <hip/hip_runtime.h>

// 4-qubit, 2-layer RY/CNOT circuit + Z-expectations + 4->2 linear head.
// TWO batch elements per thread, every scalar as a float2 ext-vector so the
// compiler emits packed fp32 (v_pk_fma_f32) — doubles fp32 throughput and
// pushes compute below the 8 us memory floor for this kernel.
//
// Index convention: s bit (8>>q) is qubit q (axis 1+q of the (B,2,2,2,2) ref).
// Layer-2 RYs fused into readout:
//   <Z_q>(R phi) = cos(th_q)*sum(phi0^2-phi1^2) - 2 sin(th_q)*sum(phi0*phi1).

typedef float v2 __attribute__((ext_vector_type(2)));
typedef float vfloat4 __attribute__((ext_vector_type(4)));

#define FMA2(A, B, C) __builtin_elementwise_fma((v2)(A), (v2)(B), (v2)(C))

template<int BIT>
__device__ __forceinline__ void apply_ry(v2 (&a)[16], float c, float s) {
#pragma unroll
    for (int i = 0; i < 16; ++i) {
        if ((i & BIT) == 0) {
            v2 a0 = a[i];
            v2 a1 = a[i | BIT];
            a[i]       = FMA2(c, a0, -(s * a1));  // c*a0 - s*a1
            a[i | BIT] = FMA2(s, a0,  (c * a1));  // s*a0 + c*a1
        }
    }
}

template<int CBIT, int TBIT>
__device__ __forceinline__ void apply_cnot(v2 (&a)[16]) {
#pragma unroll
    for (int i = 0; i < 16; ++i) {
        if ((i & CBIT) != 0 && (i & TBIT) == 0) {
            v2 t = a[i];
            a[i] = a[i | TBIT];
            a[i | TBIT] = t;
        }
    }
}

__global__ __launch_bounds__(256) void qsim_kernel(
    const vfloat4* __restrict__ x4,   // (B,4) as float4 rows
    const float*  __restrict__ wts,   // (2,4) circuit weights
    const float*  __restrict__ W,     // (2,4) linear weights
    const float*  __restrict__ bias,  // (2,)
    vfloat4*      __restrict__ out4,  // (B,2) as float4 per 2 rows
    int Bhalf)                        // B/2 threads
{
    int i = blockIdx.x * blockDim.x + threadIdx.x;
    if (i >= Bhalf) return;

    // ---- uniform (batch-independent) precompute ----
    float cw[4], sw[4];                 // layer-1 half-angle trig
#pragma unroll
    for (int q = 0; q < 4; ++q) {
        __sincosf(0.5f * wts[q], &sw[q], &cw[q]);
    }
    float wc0[4], wc1[4], wsn0[4], wsn1[4];  // layer-2 fused coefficients
#pragma unroll
    for (int q = 0; q < 4; ++q) {
        float S, C;
        __sincosf(wts[4 + q], &S, &C);       // FULL angle for the fused form
        wc0[q]  = W[q]     * C;
        wc1[q]  = W[4 + q] * C;
        wsn0[q] = -2.0f * W[q]     * S;
        wsn1[q] = -2.0f * W[4 + q] * S;
    }
    float b0 = bias[0], b1 = bias[1];

    // ---- per-sample initial RYs on |0000> for elements 2i, 2i+1 ----
    vfloat4 xA = __builtin_nontemporal_load(&x4[2 * i]);
    vfloat4 xB = __builtin_nontemporal_load(&x4[2 * i + 1]);

    v2 c[4], s[4];
#pragma unroll
    for (int q = 0; q < 4; ++q) {
        float sa, ca, sb, cb;
        __sincosf(0.5f * xA[q], &sa, &ca);
        __sincosf(0.5f * xB[q], &sb, &cb);
        c[q].x = ca; c[q].y = cb;
        s[q].x = sa; s[q].y = sb;
    }

    // rank-1 product state
    v2 a[16];
    {
        v2 p00 = c[0] * c[1], p01 = c[0] * s[1], p10 = s[0] * c[1], p11 = s[0] * s[1];
        v2 q00 = c[2] * c[3], q01 = c[2] * s[3], q10 = s[2] * c[3], q11 = s[2] * s[3];
        a[ 0] = p00 * q00; a[ 1] = p00 * q01; a[ 2] = p00 * q10; a[ 3] = p00 * q11;
        a[ 4] = p01 * q00; a[ 5] = p01 * q01; a[ 6] = p01 * q10; a[ 7] = p01 * q11;
        a[ 8] = p10 * q00; a[ 9] = p10 * q01; a[10] = p10 * q10; a[11] = p10 * q11;
        a[12] = p11 * q00; a[13] = p11 * q01; a[14] = p11 * q10; a[15] = p11 * q11;
    }

    // ---- layer 1: CNOT ring (free renames) + 4 RYs ----
    apply_cnot<8, 4>(a);
    apply_cnot<4, 2>(a);
    apply_cnot<2, 1>(a);
    apply_cnot<1, 8>(a);
    apply_ry<8>(a, cw[0], sw[0]);
    apply_ry<4>(a, cw[1], sw[1]);
    apply_ry<2>(a, cw[2], sw[2]);
    apply_ry<1>(a, cw[3], sw[3]);

    // ---- layer 2 CNOTs (free); RYs fused into readout ----
    apply_cnot<8, 4>(a);
    apply_cnot<4, 2>(a);
    apply_cnot<2, 1>(a);
    apply_cnot<1, 8>(a);

    // ---- cross terms xz_q = sum over (i, i|bit) pairs of a_i * a_j ----
    v2 xz0 = a[0] * a[8];
#pragma unroll
    for (int t = 1; t < 8; ++t) xz0 = FMA2(a[t], a[t + 8], xz0);

    v2 xz1 = a[0] * a[4];
    xz1 = FMA2(a[1], a[5], xz1);
    xz1 = FMA2(a[2], a[6], xz1);
    xz1 = FMA2(a[3], a[7], xz1);
    xz1 = FMA2(a[8], a[12], xz1);
    xz1 = FMA2(a[9], a[13], xz1);
    xz1 = FMA2(a[10], a[14], xz1);
    xz1 = FMA2(a[11], a[15], xz1);

    v2 xz2 = a[0] * a[2];
    xz2 = FMA2(a[1],  a[3],  xz2);
    xz2 = FMA2(a[4],  a[6],  xz2);
    xz2 = FMA2(a[5],  a[7],  xz2);
    xz2 = FMA2(a[8],  a[10], xz2);
    xz2 = FMA2(a[9],  a[11], xz2);
    xz2 = FMA2(a[12], a[14], xz2);
    xz2 = FMA2(a[13], a[15], xz2);

    v2 xz3 = a[0] * a[1];
    xz3 = FMA2(a[2],  a[3],  xz3);
    xz3 = FMA2(a[4],  a[5],  xz3);
    xz3 = FMA2(a[6],  a[7],  xz3);
    xz3 = FMA2(a[8],  a[9],  xz3);
    xz3 = FMA2(a[10], a[11], xz3);
    xz3 = FMA2(a[12], a[13], xz3);
    xz3 = FMA2(a[14], a[15], xz3);

    // ---- squared amplitudes + signed-sum (Walsh) tree for dz_q ----
    v2 p[16];
#pragma unroll
    for (int t = 0; t < 16; ++t) p[t] = a[t] * a[t];

    v2 A[8], D[8];
#pragma unroll
    for (int t = 0; t < 8; ++t) { A[t] = p[t] + p[t + 8]; D[t] = p[t] - p[t + 8]; }
    v2 dz0 = ((D[0] + D[1]) + (D[2] + D[3])) + ((D[4] + D[5]) + (D[6] + D[7]));

    v2 A2[4], D2[4];
#pragma unroll
    for (int t = 0; t < 4; ++t) { A2[t] = A[t] + A[t + 4]; D2[t] = A[t] - A[t + 4]; }
    v2 dz1 = (D2[0] + D2[1]) + (D2[2] + D2[3]);
    v2 dz2 = (A2[0] - A2[2]) + (A2[1] - A2[3]);
    v2 dz3 = (A2[0] + A2[2]) - (A2[1] + A2[3]);

    // ---- fused head: out_j = b_j + sum_q wc_j[q]*dz_q + wsn_j[q]*xz_q ----
    v2 o0 = (v2)(b0);
    o0 = FMA2(wc0[0], dz0, o0);
    o0 = FMA2(wc0[1], dz1, o0);
    o0 = FMA2(wc0[2], dz2, o0);
    o0 = FMA2(wc0[3], dz3, o0);
    o0 = FMA2(wsn0[0], xz0, o0);
    o0 = FMA2(wsn0[1], xz1, o0);
    o0 = FMA2(wsn0[2], xz2, o0);
    o0 = FMA2(wsn0[3], xz3, o0);

    v2 o1 = (v2)(b1);
    o1 = FMA2(wc1[0], dz0, o1);
    o1 = FMA2(wc1[1], dz1, o1);
    o1 = FMA2(wc1[2], dz2, o1);
    o1 = FMA2(wc1[3], dz3, o1);
    o1 = FMA2(wsn1[0], xz0, o1);
    o1 = FMA2(wsn1[1], xz1, o1);
    o1 = FMA2(wsn1[2], xz2, o1);
    o1 = FMA2(wsn1[3], xz3, o1);

    // elem A -> (o0.x, o1.x), elem B -> (o0.y, o1.y); one 16B coalesced store
    vfloat4 o;
    o.x = o0.x; o.y = o1.x; o.z = o0.y; o.w = o1.y;
    __builtin_nontemporal_store(o, &out4[i]);
}

extern "C" void kernel_launch(void* const* d_in, const int* in_sizes, int n_in,
                              void* d_out, int out_size, void* d_ws, size_t ws_size,
                              hipStream_t stream) {
    const float* x    = (const float*)d_in[0];  // (B,4)
    const float* wts  = (const float*)d_in[1];  // (2,4)
    const float* W    = (const float*)d_in[2];  // (2,4)
    const float* bias = (const float*)d_in[3];  // (2,)
    float* out = (float*)d_out;                 // (B,2)

    int B = in_sizes[0] / 4;
    int Bhalf = B / 2;                          // B = 2^21, even
    int block = 256;
    int grid = (Bhalf + block - 1) / block;
    qsim_kernel<<<grid, block, 0, stream>>>(
        (const vfloat4*)x, wts, W, bias, (vfloat4*)out, Bhalf);
}